// Round 1
// baseline (152.844 us; speedup 1.0000x reference)
//
#include <hip/hip_runtime.h>

// B=4, N=2048, C=256, ic=128.  Algebra (validated rounds 1-3 + this round):
//   T=lin(aim,theta) P=lin(detect,phi) Gd=lin(detect,g) Ga=lin(aim,g2)   [bf16]
//   X_v := per-batch view [128,4096] of [2048,256] (pure reshape)
//   S_aT = Gd_v @ P_v^T ; S_bT = Ga_v @ T_v^T        [128,128] fp32 (split-K + reduce)
// Round 4 fusion: out_aim[r,d] = (1/4096)*sum_k S_aT[r/16,k]*TW[16k+(r%16),d] + Wb[d] + aim[r,d]
//   with TW = T @ W^T  (and symmetrically out_det from S_bT, PQ = P @ Q^T).
// This removes the NA/ND intermediates (8 MB round trip) and merges nand+final
// into one `combine` kernel; TW/PQ GEMMs ride as extra blocks in the s_part
// stage (which was 1 block/CU underoccupied). 6 kernels -> 5.

typedef __attribute__((ext_vector_type(4))) float  f32x4;
typedef __attribute__((ext_vector_type(8))) __bf16 bf16x8;
typedef __attribute__((ext_vector_type(8))) unsigned short u16x8;
typedef __attribute__((ext_vector_type(4))) unsigned short u16x4;

__device__ inline unsigned short f2bf(float f) {
    union { float f; unsigned u; } c; c.f = f;
    unsigned r = c.u + 0x7FFF + ((c.u >> 16) & 1);   // RNE
    return (unsigned short)(r >> 16);
}
__device__ inline bf16x8 ldfrag(const unsigned short* p) {
    return __builtin_bit_cast(bf16x8, *(const u16x8*)p);
}

// ---------------- kernel 0: fp32 -> bf16 prep --------------------------------
// dst layout: [6][65536] weights (g,g2,th,ph,W,Q), then aim [2M], detect [2M].
// grid (256, 8), block 256.
__global__ __launch_bounds__(256)
void prep_kernel(const float* __restrict__ g_w, const float* __restrict__ g2_w,
                 const float* __restrict__ th_w, const float* __restrict__ ph_w,
                 const float* __restrict__ W_w, const float* __restrict__ Q_w,
                 const float* __restrict__ aim, const float* __restrict__ detect,
                 unsigned short* __restrict__ dst)
{
    const int z = blockIdx.y;
    const float* src; size_t n4; unsigned short* o;
    if (z == 0)      { src = g_w;    n4 = 16384;  o = dst; }
    else if (z == 1) { src = g2_w;   n4 = 16384;  o = dst + 65536; }
    else if (z == 2) { src = th_w;   n4 = 16384;  o = dst + 2 * 65536; }
    else if (z == 3) { src = ph_w;   n4 = 16384;  o = dst + 3 * 65536; }
    else if (z == 4) { src = W_w;    n4 = 16384;  o = dst + 4 * 65536; }
    else if (z == 5) { src = Q_w;    n4 = 16384;  o = dst + 5 * 65536; }
    else if (z == 6) { src = aim;    n4 = 524288; o = dst + 6 * 65536; }
    else             { src = detect; n4 = 524288; o = dst + 6 * 65536 + 2097152; }
    const size_t stride = (size_t)gridDim.x * 256;
    for (size_t i = blockIdx.x * 256 + threadIdx.x; i < n4; i += stride) {
        float4 v = ((const float4*)src)[i];
        u16x4 p; p[0]=f2bf(v.x); p[1]=f2bf(v.y); p[2]=f2bf(v.z); p[3]=f2bf(v.w);
        ((u16x4*)o)[i] = p;
    }
}

// ---------------- kernel 1: four input linears (all-bf16 staging) ------------
// grid (2,128,2): x=set, y=m-tile(64), z=input(0:aim,1:detect). Tile 64x256, BK=32.
__global__ __launch_bounds__(256)
void lin4_kernel(const unsigned short* __restrict__ Abf, const unsigned short* __restrict__ Dbf,
                 const unsigned short* __restrict__ Wb,   // [6][65536]
                 const float* __restrict__ b_g, const float* __restrict__ b_g2,
                 const float* __restrict__ b_th, const float* __restrict__ b_ph,
                 unsigned short* __restrict__ T,  unsigned short* __restrict__ Ga,
                 unsigned short* __restrict__ P,  unsigned short* __restrict__ Gd)
{
    const int z = blockIdx.z, set = blockIdx.x;
    const unsigned short* A = z ? Dbf : Abf;
    const int wslot = z ? (set ? 0 : 3) : (set ? 1 : 2);   // g / ph / g2 / th
    const unsigned short* Wm = Wb + (size_t)wslot * 65536;
    const float* Bv = z ? (set ? b_g : b_ph) : (set ? b_g2 : b_th);
    unsigned short* O = z ? (set ? Gd : P) : (set ? Ga : T);
    const int m0 = blockIdx.y * 64;

    __shared__ unsigned short As[64][40];    // [m][k] bf16, stride 40 (80B, 16B-mult)
    __shared__ unsigned short Bs[256][40];   // [n][k]

    const int tid = threadIdx.x, lane = tid & 63, w = tid >> 6;
    const int wr = w >> 1, wc = w & 1, q = lane >> 4, ln = lane & 15;

    f32x4 acc[2][8] = {};

    for (int k0 = 0; k0 < 256; k0 += 32) {
        {                                        // A: 64x32 bf16 = 256 u16x8
            int row = tid >> 2, c8 = tid & 3;
            *(u16x8*)&As[row][c8 * 8] = *(const u16x8*)(A + (size_t)(m0 + row) * 256 + k0 + c8 * 8);
        }
        #pragma unroll
        for (int i = 0; i < 4; ++i) {            // W: 256x32 bf16 = 1024 u16x8
            int c = tid + i * 256, row = c >> 2, c8 = c & 3;
            *(u16x8*)&Bs[row][c8 * 8] = *(const u16x8*)(Wm + (size_t)row * 256 + k0 + c8 * 8);
        }
        __syncthreads();
        bf16x8 af[2], bb[8];
        #pragma unroll
        for (int i = 0; i < 2; ++i) af[i] = ldfrag(&As[wr * 32 + i * 16 + ln][q * 8]);
        #pragma unroll
        for (int j = 0; j < 8; ++j) bb[j] = ldfrag(&Bs[wc * 128 + j * 16 + ln][q * 8]);
        #pragma unroll
        for (int i = 0; i < 2; ++i)
            #pragma unroll
            for (int j = 0; j < 8; ++j)
                acc[i][j] = __builtin_amdgcn_mfma_f32_16x16x32_bf16(af[i], bb[j], acc[i][j], 0, 0, 0);
        __syncthreads();
    }

    #pragma unroll
    for (int i = 0; i < 2; ++i)
        #pragma unroll
        for (int j = 0; j < 8; ++j) {
            int n = wc * 128 + j * 16 + ln;
            float bias = Bv[n];
            #pragma unroll
            for (int r = 0; r < 4; ++r) {
                int m = m0 + wr * 32 + i * 16 + q * 4 + r;
                O[(size_t)m * 256 + n] = f2bf(acc[i][j][r] + bias);
            }
        }
}

// ---------------- kernel 2: S partials (split-K)  +  TW/PQ GEMMs ------------
// grid (512):
//   bx < 256 : s_part  — bx = which*128 + batch*32 + chunk (KC=128). Tile 128x128.
//   bx >= 256: twpq    — side = (bx-256)>>7 (0:TW=T@W^T, 1:PQ=P@Q^T), mtile=(bx-256)&127.
//              Tile 64x256, BK=32 (lin4 structure, no bias, bf16 out).
__global__ __launch_bounds__(256)
void mid_kernel(const unsigned short* __restrict__ Gd, const unsigned short* __restrict__ P,
                const unsigned short* __restrict__ Ga, const unsigned short* __restrict__ T,
                const unsigned short* __restrict__ Wb,   // slots 4 (W), 5 (Q)
                float* __restrict__ Spart,
                unsigned short* __restrict__ TW, unsigned short* __restrict__ PQ)
{
    __shared__ unsigned short lds[18432];    // 36864 B: max(s_part 2*[128][72], twpq [64][40]+[256][40])

    const int tid = threadIdx.x, lane = tid & 63, w = tid >> 6;
    const int wr = w >> 1, wc = w & 1, q = lane >> 4, ln = lane & 15;

    if (blockIdx.x < 256) {
        // ------------------ s_part path ------------------
        const int bz = blockIdx.x;
        const int which = bz >> 7, rem = bz & 127, batch = rem >> 5, chunk = rem & 31;
        const unsigned short* A = (which ? Ga : Gd) + (size_t)batch * 524288;
        const unsigned short* B = (which ? T  : P ) + (size_t)batch * 524288;
        float* out = Spart + ((size_t)(which * 4 + batch) * 32 + chunk) * 16384;
        const int kbeg = chunk * 128;

        unsigned short (*As)[72] = (unsigned short (*)[72])lds;
        unsigned short (*Bs)[72] = (unsigned short (*)[72])(lds + 9216);

        f32x4 acc[4][4] = {};

        for (int kk = 0; kk < 2; ++kk) {
            const int k0 = kbeg + kk * 64;
            #pragma unroll
            for (int i = 0; i < 4; ++i) {            // 128x64 bf16 = 1024 u16x8 each
                int c = tid + i * 256, row = c >> 3, c8 = c & 7;
                *(u16x8*)&As[row][c8 * 8] = *(const u16x8*)(A + (size_t)row * 4096 + k0 + c8 * 8);
                *(u16x8*)&Bs[row][c8 * 8] = *(const u16x8*)(B + (size_t)row * 4096 + k0 + c8 * 8);
            }
            __syncthreads();
            #pragma unroll
            for (int ks = 0; ks < 2; ++ks) {
                bf16x8 af[4], bb[4];
                #pragma unroll
                for (int i = 0; i < 4; ++i) af[i] = ldfrag(&As[wr * 64 + i * 16 + ln][ks * 32 + q * 8]);
                #pragma unroll
                for (int j = 0; j < 4; ++j) bb[j] = ldfrag(&Bs[wc * 64 + j * 16 + ln][ks * 32 + q * 8]);
                #pragma unroll
                for (int i = 0; i < 4; ++i)
                    #pragma unroll
                    for (int j = 0; j < 4; ++j)
                        acc[i][j] = __builtin_amdgcn_mfma_f32_16x16x32_bf16(af[i], bb[j], acc[i][j], 0, 0, 0);
            }
            __syncthreads();
        }

        #pragma unroll
        for (int i = 0; i < 4; ++i)
            #pragma unroll
            for (int j = 0; j < 4; ++j)
                #pragma unroll
                for (int r = 0; r < 4; ++r) {
                    int m = wr * 64 + i * 16 + q * 4 + r, n = wc * 64 + j * 16 + ln;
                    out[m * 128 + n] = acc[i][j][r];
                }
    } else {
        // ------------------ TW/PQ path ------------------
        const int bx = blockIdx.x - 256;
        const int side = bx >> 7, mtile = bx & 127;
        const unsigned short* A = side ? P : T;
        const unsigned short* Wm = Wb + (size_t)(4 + side) * 65536;
        unsigned short* O = side ? PQ : TW;
        const int m0 = mtile * 64;

        unsigned short (*As)[40] = (unsigned short (*)[40])lds;               // [64][40]
        unsigned short (*Bs)[40] = (unsigned short (*)[40])(lds + 64 * 40);   // [256][40]

        f32x4 acc[2][8] = {};

        for (int k0 = 0; k0 < 256; k0 += 32) {
            {                                        // A: 64x32 bf16 = 256 u16x8
                int row = tid >> 2, c8 = tid & 3;
                *(u16x8*)&As[row][c8 * 8] = *(const u16x8*)(A + (size_t)(m0 + row) * 256 + k0 + c8 * 8);
            }
            #pragma unroll
            for (int i = 0; i < 4; ++i) {            // W: 256x32 bf16 = 1024 u16x8
                int c = tid + i * 256, row = c >> 2, c8 = c & 3;
                *(u16x8*)&Bs[row][c8 * 8] = *(const u16x8*)(Wm + (size_t)row * 256 + k0 + c8 * 8);
            }
            __syncthreads();
            bf16x8 af[2], bb[8];
            #pragma unroll
            for (int i = 0; i < 2; ++i) af[i] = ldfrag(&As[wr * 32 + i * 16 + ln][q * 8]);
            #pragma unroll
            for (int j = 0; j < 8; ++j) bb[j] = ldfrag(&Bs[wc * 128 + j * 16 + ln][q * 8]);
            #pragma unroll
            for (int i = 0; i < 2; ++i)
                #pragma unroll
                for (int j = 0; j < 8; ++j)
                    acc[i][j] = __builtin_amdgcn_mfma_f32_16x16x32_bf16(af[i], bb[j], acc[i][j], 0, 0, 0);
            __syncthreads();
        }

        #pragma unroll
        for (int i = 0; i < 2; ++i)
            #pragma unroll
            for (int j = 0; j < 8; ++j) {
                int n = wc * 128 + j * 16 + ln;
                #pragma unroll
                for (int r = 0; r < 4; ++r) {
                    int m = m0 + wr * 32 + i * 16 + q * 4 + r;
                    O[(size_t)m * 256 + n] = f2bf(acc[i][j][r]);
                }
            }
    }
}

// ---------------- kernel 3: reduce S partials -> bf16, pre-scaled ------------
// grid (512): 131072 outputs, one per thread. Spart layout: [which][batch][32][128][128].
__global__ __launch_bounds__(256)
void sred_kernel(const float* __restrict__ Spart, unsigned short* __restrict__ Sbf)
{
    const int idx = blockIdx.x * 256 + threadIdx.x;
    const int c = idx >> 14, e = idx & 16383;
    float s = 0.f;
    #pragma unroll
    for (int k = 0; k < 32; ++k) s += Spart[((size_t)(c * 32 + k) << 14) + e];
    Sbf[idx] = f2bf(s * (1.0f / 4096.0f));
}

// ---------------- kernel 4: combine  out = S~ @ TW_q + bias + residual -------
// out_rows r = 16*i + q :  out[r,d] = sum_k S~[i,k] * TW[16k+q, d] + bias[d] + R[r,d]
// grid (2,16,8): x=d-tile(128), y=q, z=which*4+batch. Block tile 128(i) x 128(d), K=128.
__global__ __launch_bounds__(256)
void combine_kernel(const unsigned short* __restrict__ Sbf,   // [2][4][128][128] bf16, pre-scaled /4096
                    const unsigned short* __restrict__ TW, const unsigned short* __restrict__ PQ,
                    const float* __restrict__ W_b, const float* __restrict__ Q_b,
                    const float* __restrict__ aim, const float* __restrict__ detect,
                    float* __restrict__ out_aim, float* __restrict__ out_det)
{
    const int which = blockIdx.z >> 2, batch = blockIdx.z & 3;
    const int qq = blockIdx.y, d0 = blockIdx.x * 128;
    const unsigned short* Sm = Sbf + (size_t)(which * 4 + batch) * 16384;
    const unsigned short* Bsrc = (which ? PQ : TW) + (size_t)batch * 524288;
    const float* Bv = which ? Q_b : W_b;
    const float* R  = (which ? detect : aim) + (size_t)batch * 524288;
    float* O = (which ? out_det : out_aim) + (size_t)batch * 524288;

    __shared__ unsigned short As[128][72];   // S~ [i][k]
    __shared__ unsigned short Bs[128][72];   // TW_q^T [d][k]  (transposed during staging)

    const int tid = threadIdx.x, lane = tid & 63, w = tid >> 6;
    const int wr = w >> 1, wc = w & 1, q = lane >> 4, ln = lane & 15;

    f32x4 acc[4][4] = {};

    for (int kk = 0; kk < 2; ++kk) {
        const int k0 = kk * 64;
        #pragma unroll
        for (int i = 0; i < 4; ++i) {            // A: 128x64 bf16 = 1024 u16x8
            int c = tid + i * 256, row = c >> 3, c8 = c & 7;
            *(u16x8*)&As[row][c8 * 8] = *(const u16x8*)(Sm + (size_t)row * 128 + k0 + c8 * 8);
        }
        #pragma unroll
        for (int i = 0; i < 4; ++i) {            // B: gather rows 16k+q, transpose to [d][k]
            int c = tid + i * 256, krow = c >> 4, dc = (c & 15) * 8;
            int gr = 16 * (k0 + krow) + qq;
            u16x8 v = *(const u16x8*)(Bsrc + (size_t)gr * 256 + d0 + dc);
            #pragma unroll
            for (int jj = 0; jj < 8; ++jj) Bs[dc + jj][krow] = v[jj];
        }
        __syncthreads();
        #pragma unroll
        for (int ks = 0; ks < 2; ++ks) {
            bf16x8 af[4], bb[4];
            #pragma unroll
            for (int i = 0; i < 4; ++i) af[i] = ldfrag(&As[wr * 64 + i * 16 + ln][ks * 32 + q * 8]);
            #pragma unroll
            for (int j = 0; j < 4; ++j) bb[j] = ldfrag(&Bs[wc * 64 + j * 16 + ln][ks * 32 + q * 8]);
            #pragma unroll
            for (int i = 0; i < 4; ++i)
                #pragma unroll
                for (int j = 0; j < 4; ++j)
                    acc[i][j] = __builtin_amdgcn_mfma_f32_16x16x32_bf16(af[i], bb[j], acc[i][j], 0, 0, 0);
        }
        __syncthreads();
    }

    #pragma unroll
    for (int i = 0; i < 4; ++i)
        #pragma unroll
        for (int j = 0; j < 4; ++j) {
            int d = d0 + wc * 64 + j * 16 + ln;
            float bias = Bv[d];
            #pragma unroll
            for (int r = 0; r < 4; ++r) {
                int iS = wr * 64 + i * 16 + q * 4 + r;
                size_t off = (size_t)(16 * iS + qq) * 256 + d;
                O[off] = acc[i][j][r] + bias + R[off];
            }
        }
}

extern "C" void kernel_launch(void* const* d_in, const int* in_sizes, int n_in,
                              void* d_out, int out_size, void* d_ws, size_t ws_size,
                              hipStream_t stream)
{
    const float* detect = (const float*)d_in[0];
    const float* aim    = (const float*)d_in[1];
    const float* g_w  = (const float*)d_in[2];  const float* g_b  = (const float*)d_in[3];
    const float* g2_w = (const float*)d_in[4];  const float* g2_b = (const float*)d_in[5];
    const float* th_w = (const float*)d_in[6];  const float* th_b = (const float*)d_in[7];
    const float* ph_w = (const float*)d_in[8];  const float* ph_b = (const float*)d_in[9];
    const float* W_w  = (const float*)d_in[10]; const float* W_b  = (const float*)d_in[11];
    const float* Q_w  = (const float*)d_in[12]; const float* Q_b  = (const float*)d_in[13];

    const size_t TOT = 8192L * 256;   // 2,097,152 elems per tensor

    unsigned short* ws16 = (unsigned short*)d_ws;
    unsigned short* Wbf = ws16;                 // [6][65536]: g,g2,th,ph,W,Q
    unsigned short* Abf = Wbf + 6 * 65536;      // aim bf16
    unsigned short* Dbf = Abf + TOT;            // detect bf16
    unsigned short* T   = Dbf + TOT;
    unsigned short* P   = T  + TOT;
    unsigned short* Gd  = P  + TOT;
    unsigned short* Ga  = Gd + TOT;
    unsigned short* TW  = Ga + TOT;             // T @ W^T  bf16 [8192,256]
    unsigned short* PQ  = TW + TOT;             // P @ Q^T  bf16 [8192,256]
    unsigned short* Sbf = PQ + TOT;             // [2][4][128][128] bf16 (pre-scaled)
    float* Spart = (float*)(Sbf + 131072);      // [2][4][32][128][128] fp32

    float* out_det = (float*)d_out;
    float* out_aim = out_det + TOT;

    prep_kernel<<<dim3(256, 8), 256, 0, stream>>>(
        g_w, g2_w, th_w, ph_w, W_w, Q_w, aim, detect, Wbf);
    lin4_kernel<<<dim3(2, 128, 2), 256, 0, stream>>>(
        Abf, Dbf, Wbf, g_b, g2_b, th_b, ph_b, T, Ga, P, Gd);
    mid_kernel<<<dim3(512), 256, 0, stream>>>(Gd, P, Ga, T, Wbf, Spart, TW, PQ);
    sred_kernel<<<dim3(512), 256, 0, stream>>>(Spart, Sbf);
    combine_kernel<<<dim3(2, 16, 8), 256, 0, stream>>>(
        Sbf, TW, PQ, W_b, Q_b, aim, detect, out_aim, out_det);
}

// Round 2
// 143.236 us; speedup vs baseline: 1.0671x; 1.0671x over previous
//
#include <hip/hip_runtime.h>

// B=4, N=2048, C=256, ic=128.  Algebra (validated rounds 1-4):
//   T=lin(aim,theta) P=lin(detect,phi) Gd=lin(detect,g) Ga=lin(aim,g2)   [bf16]
//   X_v := per-batch view [128,4096] of [2048,256] (pure reshape)
//   S_aT = Gd_v @ P_v^T ; S_bT = Ga_v @ T_v^T        [128,128] fp32 (split-K + reduce)
//   out_aim[r,d] = (1/4096)*sum_k S_aT[r/16,k]*TW[16k+(r%16),d] + Wb[d] + aim[r,d]
//   with TW = T @ W^T  (and symmetrically out_det from S_bT, PQ = P @ Q^T).
// Round 5 (occupancy repair of the round-4 fusion):
//   - combine: i-split -> 512 blocks (2/CU), tile 64x128          (was 256 blocks, 1/CU)
//   - s_part: 16 chunks of KC=256, tile 64x128 -> Spart halves to 8.4 MB
//   - twpq:   n-split -> 512 blocks of 64x128 (balances mid stage, 768 blocks total)

typedef __attribute__((ext_vector_type(4))) float  f32x4;
typedef __attribute__((ext_vector_type(8))) __bf16 bf16x8;
typedef __attribute__((ext_vector_type(8))) unsigned short u16x8;
typedef __attribute__((ext_vector_type(4))) unsigned short u16x4;

__device__ inline unsigned short f2bf(float f) {
    union { float f; unsigned u; } c; c.f = f;
    unsigned r = c.u + 0x7FFF + ((c.u >> 16) & 1);   // RNE
    return (unsigned short)(r >> 16);
}
__device__ inline bf16x8 ldfrag(const unsigned short* p) {
    return __builtin_bit_cast(bf16x8, *(const u16x8*)p);
}

// ---------------- kernel 0: fp32 -> bf16 prep --------------------------------
// dst layout: [6][65536] weights (g,g2,th,ph,W,Q), then aim [2M], detect [2M].
// grid (256, 8), block 256.
__global__ __launch_bounds__(256)
void prep_kernel(const float* __restrict__ g_w, const float* __restrict__ g2_w,
                 const float* __restrict__ th_w, const float* __restrict__ ph_w,
                 const float* __restrict__ W_w, const float* __restrict__ Q_w,
                 const float* __restrict__ aim, const float* __restrict__ detect,
                 unsigned short* __restrict__ dst)
{
    const int z = blockIdx.y;
    const float* src; size_t n4; unsigned short* o;
    if (z == 0)      { src = g_w;    n4 = 16384;  o = dst; }
    else if (z == 1) { src = g2_w;   n4 = 16384;  o = dst + 65536; }
    else if (z == 2) { src = th_w;   n4 = 16384;  o = dst + 2 * 65536; }
    else if (z == 3) { src = ph_w;   n4 = 16384;  o = dst + 3 * 65536; }
    else if (z == 4) { src = W_w;    n4 = 16384;  o = dst + 4 * 65536; }
    else if (z == 5) { src = Q_w;    n4 = 16384;  o = dst + 5 * 65536; }
    else if (z == 6) { src = aim;    n4 = 524288; o = dst + 6 * 65536; }
    else             { src = detect; n4 = 524288; o = dst + 6 * 65536 + 2097152; }
    const size_t stride = (size_t)gridDim.x * 256;
    for (size_t i = blockIdx.x * 256 + threadIdx.x; i < n4; i += stride) {
        float4 v = ((const float4*)src)[i];
        u16x4 p; p[0]=f2bf(v.x); p[1]=f2bf(v.y); p[2]=f2bf(v.z); p[3]=f2bf(v.w);
        ((u16x4*)o)[i] = p;
    }
}

// ---------------- kernel 1: four input linears (all-bf16 staging) ------------
// grid (2,128,2): x=set, y=m-tile(64), z=input(0:aim,1:detect). Tile 64x256, BK=32.
__global__ __launch_bounds__(256)
void lin4_kernel(const unsigned short* __restrict__ Abf, const unsigned short* __restrict__ Dbf,
                 const unsigned short* __restrict__ Wb,   // [6][65536]
                 const float* __restrict__ b_g, const float* __restrict__ b_g2,
                 const float* __restrict__ b_th, const float* __restrict__ b_ph,
                 unsigned short* __restrict__ T,  unsigned short* __restrict__ Ga,
                 unsigned short* __restrict__ P,  unsigned short* __restrict__ Gd)
{
    const int z = blockIdx.z, set = blockIdx.x;
    const unsigned short* A = z ? Dbf : Abf;
    const int wslot = z ? (set ? 0 : 3) : (set ? 1 : 2);   // g / ph / g2 / th
    const unsigned short* Wm = Wb + (size_t)wslot * 65536;
    const float* Bv = z ? (set ? b_g : b_ph) : (set ? b_g2 : b_th);
    unsigned short* O = z ? (set ? Gd : P) : (set ? Ga : T);
    const int m0 = blockIdx.y * 64;

    __shared__ unsigned short As[64][40];    // [m][k] bf16, stride 40 (80B, 16B-mult)
    __shared__ unsigned short Bs[256][40];   // [n][k]

    const int tid = threadIdx.x, lane = tid & 63, w = tid >> 6;
    const int wr = w >> 1, wc = w & 1, q = lane >> 4, ln = lane & 15;

    f32x4 acc[2][8] = {};

    for (int k0 = 0; k0 < 256; k0 += 32) {
        {                                        // A: 64x32 bf16 = 256 u16x8
            int row = tid >> 2, c8 = tid & 3;
            *(u16x8*)&As[row][c8 * 8] = *(const u16x8*)(A + (size_t)(m0 + row) * 256 + k0 + c8 * 8);
        }
        #pragma unroll
        for (int i = 0; i < 4; ++i) {            // W: 256x32 bf16 = 1024 u16x8
            int c = tid + i * 256, row = c >> 2, c8 = c & 3;
            *(u16x8*)&Bs[row][c8 * 8] = *(const u16x8*)(Wm + (size_t)row * 256 + k0 + c8 * 8);
        }
        __syncthreads();
        bf16x8 af[2], bb[8];
        #pragma unroll
        for (int i = 0; i < 2; ++i) af[i] = ldfrag(&As[wr * 32 + i * 16 + ln][q * 8]);
        #pragma unroll
        for (int j = 0; j < 8; ++j) bb[j] = ldfrag(&Bs[wc * 128 + j * 16 + ln][q * 8]);
        #pragma unroll
        for (int i = 0; i < 2; ++i)
            #pragma unroll
            for (int j = 0; j < 8; ++j)
                acc[i][j] = __builtin_amdgcn_mfma_f32_16x16x32_bf16(af[i], bb[j], acc[i][j], 0, 0, 0);
        __syncthreads();
    }

    #pragma unroll
    for (int i = 0; i < 2; ++i)
        #pragma unroll
        for (int j = 0; j < 8; ++j) {
            int n = wc * 128 + j * 16 + ln;
            float bias = Bv[n];
            #pragma unroll
            for (int r = 0; r < 4; ++r) {
                int m = m0 + wr * 32 + i * 16 + q * 4 + r;
                O[(size_t)m * 256 + n] = f2bf(acc[i][j][r] + bias);
            }
        }
}

// ---------------- kernel 2: S partials (split-K)  +  TW/PQ GEMMs ------------
// grid (768):
//   bx < 256 : s_part — bx = which*128 + batch*32 + mhalf*16 + chunk.
//              Tile 64(m) x 128(n), KC=256 (4 stages of 64).
//   bx >= 256: twpq   — t=bx-256: side=t>>8 (0:TW=T@W^T, 1:PQ=P@Q^T),
//              mtile=(t&255)>>1, nhalf=t&1. Tile 64x128, K=256, BK=32.
__global__ __launch_bounds__(256)
void mid_kernel(const unsigned short* __restrict__ Gd, const unsigned short* __restrict__ P,
                const unsigned short* __restrict__ Ga, const unsigned short* __restrict__ T,
                const unsigned short* __restrict__ Wb,   // slots 4 (W), 5 (Q)
                float* __restrict__ Spart,
                unsigned short* __restrict__ TW, unsigned short* __restrict__ PQ)
{
    __shared__ unsigned short lds[13824];    // 27648 B: s_part [64][72]+[128][72]; twpq [64][40]+[128][40]

    const int tid = threadIdx.x, lane = tid & 63, w = tid >> 6;
    const int wr = w >> 1, wc = w & 1, q = lane >> 4, ln = lane & 15;

    if (blockIdx.x < 256) {
        // ------------------ s_part path ------------------
        const int bz = blockIdx.x;
        const int which = bz >> 7, rem = bz & 127, batch = rem >> 5;
        const int mhalf = (rem >> 4) & 1, chunk = rem & 15;
        const unsigned short* A = (which ? Ga : Gd) + (size_t)batch * 524288;
        const unsigned short* B = (which ? T  : P ) + (size_t)batch * 524288;
        float* out = Spart + ((size_t)(which * 4 + batch) * 16 + chunk) * 16384;
        const int kbeg = chunk * 256, m0 = mhalf * 64;

        unsigned short (*As)[72] = (unsigned short (*)[72])lds;               // [64][72]
        unsigned short (*Bs)[72] = (unsigned short (*)[72])(lds + 64 * 72);   // [128][72]

        f32x4 acc[2][4] = {};

        for (int kk = 0; kk < 4; ++kk) {
            const int k0 = kbeg + kk * 64;
            #pragma unroll
            for (int i = 0; i < 2; ++i) {            // A: 64x64 bf16 = 512 u16x8
                int c = tid + i * 256, row = c >> 3, c8 = c & 7;
                *(u16x8*)&As[row][c8 * 8] = *(const u16x8*)(A + (size_t)(m0 + row) * 4096 + k0 + c8 * 8);
            }
            #pragma unroll
            for (int i = 0; i < 4; ++i) {            // B: 128x64 bf16 = 1024 u16x8
                int c = tid + i * 256, row = c >> 3, c8 = c & 7;
                *(u16x8*)&Bs[row][c8 * 8] = *(const u16x8*)(B + (size_t)row * 4096 + k0 + c8 * 8);
            }
            __syncthreads();
            #pragma unroll
            for (int ks = 0; ks < 2; ++ks) {
                bf16x8 af[2], bb[4];
                #pragma unroll
                for (int i = 0; i < 2; ++i) af[i] = ldfrag(&As[wr * 32 + i * 16 + ln][ks * 32 + q * 8]);
                #pragma unroll
                for (int j = 0; j < 4; ++j) bb[j] = ldfrag(&Bs[wc * 64 + j * 16 + ln][ks * 32 + q * 8]);
                #pragma unroll
                for (int i = 0; i < 2; ++i)
                    #pragma unroll
                    for (int j = 0; j < 4; ++j)
                        acc[i][j] = __builtin_amdgcn_mfma_f32_16x16x32_bf16(af[i], bb[j], acc[i][j], 0, 0, 0);
            }
            __syncthreads();
        }

        #pragma unroll
        for (int i = 0; i < 2; ++i)
            #pragma unroll
            for (int j = 0; j < 4; ++j)
                #pragma unroll
                for (int r = 0; r < 4; ++r) {
                    int m = m0 + wr * 32 + i * 16 + q * 4 + r, n = wc * 64 + j * 16 + ln;
                    out[m * 128 + n] = acc[i][j][r];
                }
    } else {
        // ------------------ TW/PQ path ------------------
        const int t = blockIdx.x - 256;
        const int side = t >> 8, rem = t & 255, mtile = rem >> 1, nhalf = rem & 1;
        const unsigned short* A = side ? P : T;
        const unsigned short* Wm = Wb + (size_t)(4 + side) * 65536;
        unsigned short* O = side ? PQ : TW;
        const int m0 = mtile * 64, n0 = nhalf * 128;

        unsigned short (*As)[40] = (unsigned short (*)[40])lds;               // [64][40]
        unsigned short (*Bs)[40] = (unsigned short (*)[40])(lds + 64 * 40);   // [128][40]

        f32x4 acc[2][4] = {};

        for (int k0 = 0; k0 < 256; k0 += 32) {
            {                                        // A: 64x32 bf16 = 256 u16x8
                int row = tid >> 2, c8 = tid & 3;
                *(u16x8*)&As[row][c8 * 8] = *(const u16x8*)(A + (size_t)(m0 + row) * 256 + k0 + c8 * 8);
            }
            #pragma unroll
            for (int i = 0; i < 2; ++i) {            // W: 128x32 bf16 = 512 u16x8
                int c = tid + i * 256, row = c >> 2, c8 = c & 3;
                *(u16x8*)&Bs[row][c8 * 8] = *(const u16x8*)(Wm + (size_t)(n0 + row) * 256 + k0 + c8 * 8);
            }
            __syncthreads();
            bf16x8 af[2], bb[4];
            #pragma unroll
            for (int i = 0; i < 2; ++i) af[i] = ldfrag(&As[wr * 32 + i * 16 + ln][q * 8]);
            #pragma unroll
            for (int j = 0; j < 4; ++j) bb[j] = ldfrag(&Bs[wc * 64 + j * 16 + ln][q * 8]);
            #pragma unroll
            for (int i = 0; i < 2; ++i)
                #pragma unroll
                for (int j = 0; j < 4; ++j)
                    acc[i][j] = __builtin_amdgcn_mfma_f32_16x16x32_bf16(af[i], bb[j], acc[i][j], 0, 0, 0);
            __syncthreads();
        }

        #pragma unroll
        for (int i = 0; i < 2; ++i)
            #pragma unroll
            for (int j = 0; j < 4; ++j) {
                int n = n0 + wc * 64 + j * 16 + ln;
                #pragma unroll
                for (int r = 0; r < 4; ++r) {
                    int m = m0 + wr * 32 + i * 16 + q * 4 + r;
                    O[(size_t)m * 256 + n] = f2bf(acc[i][j][r]);
                }
            }
    }
}

// ---------------- kernel 3: reduce S partials -> bf16, pre-scaled ------------
// grid (512): 131072 outputs, one per thread. Spart layout: [which][batch][16][128][128].
__global__ __launch_bounds__(256)
void sred_kernel(const float* __restrict__ Spart, unsigned short* __restrict__ Sbf)
{
    const int idx = blockIdx.x * 256 + threadIdx.x;
    const int c = idx >> 14, e = idx & 16383;
    float s = 0.f;
    #pragma unroll
    for (int k = 0; k < 16; ++k) s += Spart[((size_t)(c * 16 + k) << 14) + e];
    Sbf[idx] = f2bf(s * (1.0f / 4096.0f));
}

// ---------------- kernel 4: combine  out = S~ @ TW_q + bias + residual -------
// out_rows r = 16*i + q :  out[r,d] = sum_k S~[i,k] * TW[16k+q, d] + bias[d] + R[r,d]
// grid (4,16,8): x = dtile*2+ihalf, y=q, z=which*4+batch.
// Block tile 64(i) x 128(d), K=128 (2 stages of 64).
__global__ __launch_bounds__(256)
void combine_kernel(const unsigned short* __restrict__ Sbf,   // [2][4][128][128] bf16, pre-scaled /4096
                    const unsigned short* __restrict__ TW, const unsigned short* __restrict__ PQ,
                    const float* __restrict__ W_b, const float* __restrict__ Q_b,
                    const float* __restrict__ aim, const float* __restrict__ detect,
                    float* __restrict__ out_aim, float* __restrict__ out_det)
{
    const int which = blockIdx.z >> 2, batch = blockIdx.z & 3;
    const int qq = blockIdx.y;
    const int dtile = blockIdx.x >> 1, ihalf = blockIdx.x & 1;
    const int d0 = dtile * 128, i0 = ihalf * 64;
    const unsigned short* Sm = Sbf + (size_t)(which * 4 + batch) * 16384;
    const unsigned short* Bsrc = (which ? PQ : TW) + (size_t)batch * 524288;
    const float* Bv = which ? Q_b : W_b;
    const float* R  = (which ? detect : aim) + (size_t)batch * 524288;
    float* O = (which ? out_det : out_aim) + (size_t)batch * 524288;

    __shared__ unsigned short As[64][72];    // S~ [i][k]
    __shared__ unsigned short Bs[128][72];   // TW_q^T [d][k]  (transposed during staging)

    const int tid = threadIdx.x, lane = tid & 63, w = tid >> 6;
    const int wr = w >> 1, wc = w & 1, q = lane >> 4, ln = lane & 15;

    f32x4 acc[2][4] = {};

    for (int kk = 0; kk < 2; ++kk) {
        const int k0 = kk * 64;
        #pragma unroll
        for (int i = 0; i < 2; ++i) {            // A: 64x64 bf16 = 512 u16x8
            int c = tid + i * 256, row = c >> 3, c8 = c & 7;
            *(u16x8*)&As[row][c8 * 8] = *(const u16x8*)(Sm + (size_t)(i0 + row) * 128 + k0 + c8 * 8);
        }
        #pragma unroll
        for (int i = 0; i < 4; ++i) {            // B: gather 64 rows 16k+q, transpose to [d][k]
            int c = tid + i * 256, krow = c >> 4, dc = (c & 15) * 8;
            int gr = 16 * (k0 + krow) + qq;
            u16x8 v = *(const u16x8*)(Bsrc + (size_t)gr * 256 + d0 + dc);
            #pragma unroll
            for (int jj = 0; jj < 8; ++jj) Bs[dc + jj][krow] = v[jj];
        }
        __syncthreads();
        #pragma unroll
        for (int ks = 0; ks < 2; ++ks) {
            bf16x8 af[2], bb[4];
            #pragma unroll
            for (int i = 0; i < 2; ++i) af[i] = ldfrag(&As[wr * 32 + i * 16 + ln][ks * 32 + q * 8]);
            #pragma unroll
            for (int j = 0; j < 4; ++j) bb[j] = ldfrag(&Bs[wc * 64 + j * 16 + ln][ks * 32 + q * 8]);
            #pragma unroll
            for (int i = 0; i < 2; ++i)
                #pragma unroll
                for (int j = 0; j < 4; ++j)
                    acc[i][j] = __builtin_amdgcn_mfma_f32_16x16x32_bf16(af[i], bb[j], acc[i][j], 0, 0, 0);
        }
        __syncthreads();
    }

    #pragma unroll
    for (int i = 0; i < 2; ++i)
        #pragma unroll
        for (int j = 0; j < 4; ++j) {
            int d = d0 + wc * 64 + j * 16 + ln;
            float bias = Bv[d];
            #pragma unroll
            for (int r = 0; r < 4; ++r) {
                int iS = i0 + wr * 32 + i * 16 + q * 4 + r;
                size_t off = (size_t)(16 * iS + qq) * 256 + d;
                O[off] = acc[i][j][r] + bias + R[off];
            }
        }
}

extern "C" void kernel_launch(void* const* d_in, const int* in_sizes, int n_in,
                              void* d_out, int out_size, void* d_ws, size_t ws_size,
                              hipStream_t stream)
{
    const float* detect = (const float*)d_in[0];
    const float* aim    = (const float*)d_in[1];
    const float* g_w  = (const float*)d_in[2];  const float* g_b  = (const float*)d_in[3];
    const float* g2_w = (const float*)d_in[4];  const float* g2_b = (const float*)d_in[5];
    const float* th_w = (const float*)d_in[6];  const float* th_b = (const float*)d_in[7];
    const float* ph_w = (const float*)d_in[8];  const float* ph_b = (const float*)d_in[9];
    const float* W_w  = (const float*)d_in[10]; const float* W_b  = (const float*)d_in[11];
    const float* Q_w  = (const float*)d_in[12]; const float* Q_b  = (const float*)d_in[13];

    const size_t TOT = 8192L * 256;   // 2,097,152 elems per tensor

    unsigned short* ws16 = (unsigned short*)d_ws;
    unsigned short* Wbf = ws16;                 // [6][65536]: g,g2,th,ph,W,Q
    unsigned short* Abf = Wbf + 6 * 65536;      // aim bf16
    unsigned short* Dbf = Abf + TOT;            // detect bf16
    unsigned short* T   = Dbf + TOT;
    unsigned short* P   = T  + TOT;
    unsigned short* Gd  = P  + TOT;
    unsigned short* Ga  = Gd + TOT;
    unsigned short* TW  = Ga + TOT;             // T @ W^T  bf16 [8192,256]
    unsigned short* PQ  = TW + TOT;             // P @ Q^T  bf16 [8192,256]
    unsigned short* Sbf = PQ + TOT;             // [2][4][128][128] bf16 (pre-scaled)
    float* Spart = (float*)(Sbf + 131072);      // [2][4][16][128][128] fp32

    float* out_det = (float*)d_out;
    float* out_aim = out_det + TOT;

    prep_kernel<<<dim3(256, 8), 256, 0, stream>>>(
        g_w, g2_w, th_w, ph_w, W_w, Q_w, aim, detect, Wbf);
    lin4_kernel<<<dim3(2, 128, 2), 256, 0, stream>>>(
        Abf, Dbf, Wbf, g_b, g2_b, th_b, ph_b, T, Ga, P, Gd);
    mid_kernel<<<dim3(768), 256, 0, stream>>>(Gd, P, Ga, T, Wbf, Spart, TW, PQ);
    sred_kernel<<<dim3(512), 256, 0, stream>>>(Spart, Sbf);
    combine_kernel<<<dim3(4, 16, 8), 256, 0, stream>>>(
        Sbf, TW, PQ, W_b, Q_b, aim, detect, out_aim, out_det);
}